// Round 1
// 255.306 us; speedup vs baseline: 1.0428x; 1.0428x over previous
//
#include <hip/hip_runtime.h>
#include <stdint.h>

#define BB 2
#define SS 2048
#define DD 1024
#define HH 16
#define DKK 64
#define MT (BB*SS)   // 4096 rows total

#define GSTRIDE 40   // fallback GEMM LDS row stride (elem): conflict-free frags
#define ASTRIDE 72   // attn LDS row stride (elem): conflict-free frags

using short8  = __attribute__((ext_vector_type(8))) short;   // 8 x bf16 bits (4 VGPRs)
using floatx4 = __attribute__((ext_vector_type(4))) float;
using u16x4   = __attribute__((ext_vector_type(4))) unsigned short;
typedef unsigned short u16;

__device__ __forceinline__ u16 f2b(float f) {   // RNE float->bf16
  union { float f; unsigned u; } v; v.f = f;
  return (u16)((v.u + 0x7FFFu + ((v.u >> 16) & 1u)) >> 16);
}
__device__ __forceinline__ void pack16(const float4* p, short8& lo, short8& hi) {
  float4 x0 = p[0], x1 = p[1], x2 = p[2], x3 = p[3];
  lo[0]=(short)f2b(x0.x); lo[1]=(short)f2b(x0.y); lo[2]=(short)f2b(x0.z); lo[3]=(short)f2b(x0.w);
  lo[4]=(short)f2b(x1.x); lo[5]=(short)f2b(x1.y); lo[6]=(short)f2b(x1.z); lo[7]=(short)f2b(x1.w);
  hi[0]=(short)f2b(x2.x); hi[1]=(short)f2b(x2.y); hi[2]=(short)f2b(x2.z); hi[3]=(short)f2b(x2.w);
  hi[4]=(short)f2b(x3.x); hi[5]=(short)f2b(x3.y); hi[6]=(short)f2b(x3.z); hi[7]=(short)f2b(x3.w);
}
// async global->LDS, 16B/lane; lds base wave-uniform, HW scatters lane i at +16*i
__device__ __forceinline__ void gload16(const u16* g, u16* l) {
  __builtin_amdgcn_global_load_lds(
      (const __attribute__((address_space(1))) void*)g,
      (__attribute__((address_space(3))) void*)l, 16, 0, 0);
}

// ---------------------------------------------------------------------------
// One merged cast launch: Q/K/V (2048 blk each) + Wq/Wk/Wv/Wo (512 blk each).
// ---------------------------------------------------------------------------
__global__ __launch_bounds__(256) void cast_all(
    const float* __restrict__ Qin, const float* __restrict__ Kin,
    const float* __restrict__ Vin, const float* __restrict__ Wq,
    const float* __restrict__ Wk,  const float* __restrict__ Wv,
    const float* __restrict__ Wo,
    u16* __restrict__ cQ, u16* __restrict__ cK, u16* __restrict__ cV,
    u16* __restrict__ cWq, u16* __restrict__ cWk, u16* __restrict__ cWv,
    u16* __restrict__ cWo)
{
  const int y = blockIdx.y;
  if (y >= 3 && blockIdx.x >= (DD*DD/8/256)) return;   // weights are 1M elems
  const float* s; u16* d;
  switch (y) {
    case 0: s = Qin; d = cQ;  break;
    case 1: s = Kin; d = cK;  break;
    case 2: s = Vin; d = cV;  break;
    case 3: s = Wq;  d = cWq; break;
    case 4: s = Wk;  d = cWk; break;
    case 5: s = Wv;  d = cWv; break;
    default: s = Wo; d = cWo; break;
  }
  const size_t g = (size_t)blockIdx.x * 256 + threadIdx.x;
  float4 x0 = ((const float4*)s)[g*2], x1 = ((const float4*)s)[g*2+1];
  short8 lo;
  lo[0]=(short)f2b(x0.x); lo[1]=(short)f2b(x0.y); lo[2]=(short)f2b(x0.z); lo[3]=(short)f2b(x0.w);
  lo[4]=(short)f2b(x1.x); lo[5]=(short)f2b(x1.y); lo[6]=(short)f2b(x1.z); lo[7]=(short)f2b(x1.w);
  ((short8*)d)[g] = lo;
}
__global__ __launch_bounds__(256) void cast_w3(
    const float* __restrict__ w0, const float* __restrict__ w1,
    const float* __restrict__ w2, u16* __restrict__ o)
{
  const float* s = (blockIdx.y == 0) ? w0 : (blockIdx.y == 1) ? w1 : w2;
  u16* d = o + (size_t)blockIdx.y * (DD * DD);
  const size_t g = (size_t)blockIdx.x * 256 + threadIdx.x;
  float4 x0 = ((const float4*)s)[g*2], x1 = ((const float4*)s)[g*2+1];
  short8 lo;
  lo[0]=(short)f2b(x0.x); lo[1]=(short)f2b(x0.y); lo[2]=(short)f2b(x0.z); lo[3]=(short)f2b(x0.w);
  lo[4]=(short)f2b(x1.x); lo[5]=(short)f2b(x1.y); lo[6]=(short)f2b(x1.z); lo[7]=(short)f2b(x1.w);
  ((short8*)d)[g] = lo;
}

// ---------------------------------------------------------------------------
// PRIMARY GEMM (BK=64): all-bf16, global_load_lds width-16, 2-barrier K-loop
// with HALF the barriers of BK=32. LDS rows 64 elem (128B); odd rows store
// their two 32-col halves SWAPPED (swizzle applied at the GLOBAL address so
// the linear lane->lds scatter of global_load_lds is preserved). Fragment
// readers XOR the half-select with row parity -> start banks alternate
// 4q / 16+4q across lr parity = conflict-optimal (8 phases / b128 wave read).
// ---------------------------------------------------------------------------
template<bool OUT_F32>
__device__ __forceinline__ void gemm_async(
    const u16* __restrict__ A, const u16* __restrict__ W,
    const float* __restrict__ bias, void* __restrict__ Cv,
    const int K, const int N, const int m0, const int n0, const float scale)
{
  __shared__ __align__(16) u16 sA[128*64];
  __shared__ __align__(16) u16 sB[128*64];

  const int tid  = threadIdx.x;
  const int wave = tid >> 6;
  const int lane = tid & 63;
  const int quad = lane >> 4;
  const int lr   = lane & 15;
  const int wm   = wave >> 1;
  const int wn   = wave & 1;
  const int srow = lane >> 3;                              // 0..7 within chunk
  const int swz  = (((lane & 7) ^ ((srow & 1) << 2)) << 3); // swizzled col (elems)

  floatx4 acc[4][4];
#pragma unroll
  for (int i = 0; i < 4; ++i)
#pragma unroll
    for (int j = 0; j < 4; ++j) acc[i][j] = (floatx4){0.f, 0.f, 0.f, 0.f};

  // chunk = 8 rows x 64 cols = 1KB; wave w stages chunks w, w+4, w+8, w+12
  const u16* pA[4]; const u16* pW[4];
#pragma unroll
  for (int c = 0; c < 4; ++c) {
    const int row = (wave + c*4) * 8 + srow;
    pA[c] = A + (size_t)(m0 + row) * K + swz;
    pW[c] = W + (size_t)(n0 + row) * K + swz;
  }

  const int nk = K >> 6;
  for (int kt = 0; kt < nk; ++kt) {
    const int k0 = kt << 6;
#pragma unroll
    for (int c = 0; c < 4; ++c) {
      gload16(pA[c] + k0, sA + (wave + c*4) * 512);
      gload16(pW[c] + k0, sB + (wave + c*4) * 512);
    }
    __syncthreads();   // drains vmcnt -> staging complete

#pragma unroll
    for (int h2 = 0; h2 < 2; ++h2) {     // two k-halves of the 64-wide tile
      const int csel = (quad << 3) + ((h2 ^ (lr & 1)) << 5);
      short8 af[4], bf[4];
#pragma unroll
      for (int t = 0; t < 4; ++t) {
        af[t] = *(const short8*)(sA + (wm*64 + t*16 + lr)*64 + csel);
        bf[t] = *(const short8*)(sB + (wn*64 + t*16 + lr)*64 + csel);
      }
#pragma unroll
      for (int i = 0; i < 4; ++i)
#pragma unroll
        for (int j = 0; j < 4; ++j)
          acc[i][j] = __builtin_amdgcn_mfma_f32_16x16x32_bf16(af[i], bf[j], acc[i][j], 0, 0, 0);
    }
    __syncthreads();   // reads done before next staging overwrites
  }

  // epilogue: C/D layout col (lane&15) = n, row (quad*4+reg) = m
#pragma unroll
  for (int i = 0; i < 4; ++i) {
    const int mb = m0 + wm*64 + i*16 + quad*4;
#pragma unroll
    for (int j = 0; j < 4; ++j) {
      const int n = n0 + wn*64 + j*16 + lr;
      const float bsv = bias[n];
#pragma unroll
      for (int r = 0; r < 4; ++r) {
        const size_t idx = (size_t)(mb + r) * N + n;
        const float v = (acc[i][j][r] + bsv) * scale;
        if (OUT_F32) ((float*)Cv)[idx] = v;
        else         ((u16*)Cv)[idx]   = f2b(v);
      }
    }
  }
}

__global__ __launch_bounds__(256, 3) void gemm_qkv_async(
    const u16* __restrict__ cQ, const u16* __restrict__ cK, const u16* __restrict__ cV,
    const u16* __restrict__ cWq, const u16* __restrict__ cWk, const u16* __restrict__ cWv,
    const float* __restrict__ bq, const float* __restrict__ bk, const float* __restrict__ bv,
    u16* __restrict__ oQ, u16* __restrict__ oK, u16* __restrict__ oV)
{
  const int wsel = blockIdx.x >> 3;
  const int n0 = (blockIdx.x & 7) * 128;
  const int m0 = blockIdx.y * 128;
  const u16* A; const u16* W; const float* bias; u16* C;
  if (wsel == 0)      { A = cQ; W = cWq; bias = bq; C = oQ; }
  else if (wsel == 1) { A = cK; W = cWk; bias = bk; C = oK; }
  else                { A = cV; W = cWv; bias = bv; C = oV; }
  const float scale = (wsel == 0) ? 0.125f : 1.0f;   // Q pre-scaled by 1/sqrt(dk)
  gemm_async<false>(A, W, bias, C, DD, DD, m0, n0, scale);
}

__global__ __launch_bounds__(256, 3) void gemm_out_async(
    const u16* __restrict__ A, const u16* __restrict__ cWo,
    const float* __restrict__ bias, float* __restrict__ C)
{
  gemm_async<true>(A, cWo, bias, C, DD, DD, blockIdx.y * 128, blockIdx.x * 128, 1.0f);
}

// ---------------------------------------------------------------------------
// FALLBACK GEMM core (round-7 verified): explicit staging, padded LDS.
// ---------------------------------------------------------------------------
template<bool A_BF16, bool W_BF16, bool OUT_F32>
__device__ __forceinline__ void gemm_core(
    const void* __restrict__ A, const void* __restrict__ W,
    const float* __restrict__ bias, void* __restrict__ Cv,
    const int K, const int N, const int m0, const int n0, const float scale)
{
  __shared__ __align__(16) u16 sA[128*GSTRIDE];
  __shared__ __align__(16) u16 sB[128*GSTRIDE];

  const int tid  = threadIdx.x;
  const int wave = tid >> 6;
  const int lane = tid & 63;
  const int quad = lane >> 4;
  const int lr   = lane & 15;
  const int wm   = wave >> 1;
  const int wn   = wave & 1;
  const int srow = tid >> 1;
  const int scol = (tid & 1) * 16;

  floatx4 acc[4][4];
#pragma unroll
  for (int i = 0; i < 4; ++i)
#pragma unroll
    for (int j = 0; j < 4; ++j) acc[i][j] = (floatx4){0.f, 0.f, 0.f, 0.f};

  const size_t offA = (size_t)(m0 + srow) * K + scol;
  const size_t offW = (size_t)(n0 + srow) * K + scol;

  const int nk = K >> 5;
  for (int kt = 0; kt < nk; ++kt) {
    const int k0 = kt << 5;
    short8 a0, a1, b0, b1;
    if (A_BF16) {
      const u16* p = (const u16*)A + offA + k0;
      a0 = *(const short8*)p; a1 = *(const short8*)(p + 8);
    } else {
      pack16((const float4*)((const float*)A + offA + k0), a0, a1);
    }
    if (W_BF16) {
      const u16* p = (const u16*)W + offW + k0;
      b0 = *(const short8*)p; b1 = *(const short8*)(p + 8);
    } else {
      pack16((const float4*)((const float*)W + offW + k0), b0, b1);
    }
    __syncthreads();
    *(short8*)(sA + srow * GSTRIDE + scol)     = a0;
    *(short8*)(sA + srow * GSTRIDE + scol + 8) = a1;
    *(short8*)(sB + srow * GSTRIDE + scol)     = b0;
    *(short8*)(sB + srow * GSTRIDE + scol + 8) = b1;
    __syncthreads();

    short8 af[4], bf[4];
#pragma unroll
    for (int t = 0; t < 4; ++t) {
      af[t] = *(const short8*)(sA + (wm*64 + t*16 + lr)*GSTRIDE + quad*8);
      bf[t] = *(const short8*)(sB + (wn*64 + t*16 + lr)*GSTRIDE + quad*8);
    }
#pragma unroll
    for (int i = 0; i < 4; ++i)
#pragma unroll
      for (int j = 0; j < 4; ++j)
        acc[i][j] = __builtin_amdgcn_mfma_f32_16x16x32_bf16(af[i], bf[j], acc[i][j], 0, 0, 0);
  }

#pragma unroll
  for (int i = 0; i < 4; ++i) {
    const int mb = m0 + wm*64 + i*16 + quad*4;
#pragma unroll
    for (int j = 0; j < 4; ++j) {
      const int n = n0 + wn*64 + j*16 + lr;
      const float bsv = bias[n];
#pragma unroll
      for (int r = 0; r < 4; ++r) {
        const size_t idx = (size_t)(mb + r) * N + n;
        const float v = (acc[i][j][r] + bsv) * scale;
        if (OUT_F32) ((float*)Cv)[idx] = v;
        else         ((u16*)Cv)[idx]   = f2b(v);
      }
    }
  }
}

__global__ __launch_bounds__(256, 2) void gemm_qkv_fb(
    const float* __restrict__ Qin, const float* __restrict__ Kin, const float* __restrict__ Vin,
    const u16* __restrict__ cWq, const u16* __restrict__ cWk, const u16* __restrict__ cWv,
    const float* __restrict__ bq, const float* __restrict__ bk, const float* __restrict__ bv,
    u16* __restrict__ oQ, u16* __restrict__ oK, u16* __restrict__ oV)
{
  const int wsel = blockIdx.x >> 3;
  const int n0 = (blockIdx.x & 7) * 128;
  const int m0 = blockIdx.y * 128;
  const float* A; const u16* W; const float* bias; u16* C;
  if (wsel == 0)      { A = Qin; W = cWq; bias = bq; C = oQ; }
  else if (wsel == 1) { A = Kin; W = cWk; bias = bk; C = oK; }
  else                { A = Vin; W = cWv; bias = bv; C = oV; }
  const float scale = (wsel == 0) ? 0.125f : 1.0f;
  gemm_core<false, true, false>(A, W, bias, C, DD, DD, m0, n0, scale);
}
__global__ __launch_bounds__(256, 2) void gemm_out_fb(
    const u16* __restrict__ A, const float* __restrict__ W,
    const float* __restrict__ bias, float* __restrict__ C)
{
  gemm_core<true, false, true>((const void*)A, (const void*)W, bias, C, DD, DD,
                               blockIdx.y * 128, blockIdx.x * 128, 1.0f);
}

// ---------------------------------------------------------------------------
// V transpose: pV[B,S,D] (head h cols) -> Vt[B,H,dk,S]
// ---------------------------------------------------------------------------
__global__ __launch_bounds__(256) void transpose_v(
    const u16* __restrict__ Vp, u16* __restrict__ Vt)
{
  __shared__ u16 t[64 * 65];
  const int st = blockIdx.x, h = blockIdx.y, b = blockIdx.z;

  const int r  = threadIdx.x >> 2;
  const int c0 = (threadIdx.x & 3) * 16;
  const u16* src = Vp + ((size_t)(b * SS + st * 64 + r)) * DD + h * 64 + c0;
  short8 v0 = *(const short8*)src;
  short8 v1 = *(const short8*)(src + 8);
#pragma unroll
  for (int i = 0; i < 8; ++i) {
    t[r * 65 + c0 + i]     = (u16)v0[i];
    t[r * 65 + c0 + 8 + i] = (u16)v1[i];
  }
  __syncthreads();
  union { u16 a[16]; short8 v[2]; } ob;
#pragma unroll
  for (int i = 0; i < 16; ++i) ob.a[i] = t[(c0 + i) * 65 + r];
  u16* dst = Vt + (((size_t)(b * HH + h)) * DKK + r) * SS + st * 64 + c0;
  *(short8*)dst       = ob.v[0];
  *(short8*)(dst + 8) = ob.v[1];
}

// ---------------------------------------------------------------------------
// Flash attention, q-tile 128: block = 128 Q rows of one (b,h); each wave
// handles 2 groups of 16 q-cols (transposed-S softmax, Q pre-scaled).
//
// R-occ revision:
//  * Q held in REGISTERS (loop-invariant; was re-read from sQ every kt).
//    Removes 18 KB LDS + 4 b128 LDS reads/lane/iter.
//  * sP is per-wave scratch -> no __syncthreads() needed between its write
//    and read (within-wave lgkmcnt ordering). 2 barriers/iter instead of 3.
//  * LDS 55.3 KB -> 36.9 KB: 4 blocks/CU (was 2). __launch_bounds__(256,4).
//  * XCD-bijective block swizzle (512 blocks, 512%8==0): the 16 q-tiles of
//    one (b,h) land on one XCD -> K/V tiles hit in that XCD's L2 instead of
//    being re-fetched by all 8 XCDs.
// ---------------------------------------------------------------------------
__global__ __launch_bounds__(256, 4) void attn(
    const u16* __restrict__ Qp, const u16* __restrict__ Kp,
    const u16* __restrict__ Vt, u16* __restrict__ O)
{
  __shared__ __align__(16) u16 sK[64 * ASTRIDE];
  __shared__ __align__(16) u16 sV[64 * ASTRIDE];
  __shared__ __align__(16) u16 sP[4][32 * ASTRIDE];   // per wave: 2 groups x 16 rows

  const int tid = threadIdx.x, wave = tid >> 6, lane = tid & 63;
  const int quad = lane >> 4, lr = lane & 15;

  // XCD-aware bijective swizzle: flat = (b*16+h)*16+qb over 512 blocks.
  // XCD x (round-robin flat%8) gets work ids x*64..x*64+63 = 4 full (b,h).
  const int flat = (blockIdx.z * 16 + blockIdx.y) * 16 + blockIdx.x;
  const int swzb = (flat & 7) * 64 + (flat >> 3);
  const int qb = swzb & 15;
  const int h  = (swzb >> 4) & 15;
  const int b  = swzb >> 8;
  const size_t vbase = ((size_t)(b * HH + h)) * DKK * SS;

  // Q fragments in registers: [group][k-half], loop-invariant
  short8 qf[2][2];
  {
    const u16* qbase = Qp + ((size_t)(b * SS + qb * 128)) * DD + h * 64;
#pragma unroll
    for (int g = 0; g < 2; ++g) {
      const u16* qr = qbase + (size_t)(g*64 + wave*16 + lr) * DD + quad * 8;
      qf[g][0] = *(const short8*)qr;
      qf[g][1] = *(const short8*)(qr + 32);
    }
  }

  floatx4 accO[2][4];
  float m_l[2] = { -3e38f, -3e38f }, l_l[2] = { 0.f, 0.f };
#pragma unroll
  for (int g = 0; g < 2; ++g)
#pragma unroll
    for (int t = 0; t < 4; ++t) accO[g][t] = (floatx4){0.f, 0.f, 0.f, 0.f};

  for (int kt = 0; kt < SS / 64; ++kt) {
    __syncthreads();   // prior iter's sK/sV reads done
    {
      const int r = tid >> 2, c = (tid & 3) * 16;
      const short8* sk = (const short8*)(Kp + ((size_t)(b * SS + kt * 64 + r)) * DD + h * 64 + c);
      short8* dk = (short8*)(sK + r * ASTRIDE + c);
      dk[0] = sk[0]; dk[1] = sk[1];
      const short8* sv = (const short8*)(Vt + vbase + (size_t)r * SS + kt * 64 + c);
      short8* dv = (short8*)(sV + r * ASTRIDE + c);
      dv[0] = sv[0]; dv[1] = sv[1];
    }
    __syncthreads();

#pragma unroll
    for (int g = 0; g < 2; ++g) {
      // S^T[k][q] for this wave+group's 16 q-cols: A = K rows, B = Q rows
      floatx4 st[4];
#pragma unroll
      for (int t = 0; t < 4; ++t) {
        short8 ka0 = *(const short8*)(sK + (t*16 + lr) * ASTRIDE + quad * 8);
        short8 ka1 = *(const short8*)(sK + (t*16 + lr) * ASTRIDE + 32 + quad * 8);
        floatx4 cc = (floatx4){0.f, 0.f, 0.f, 0.f};
        cc = __builtin_amdgcn_mfma_f32_16x16x32_bf16(ka0, qf[g][0], cc, 0, 0, 0);
        cc = __builtin_amdgcn_mfma_f32_16x16x32_bf16(ka1, qf[g][1], cc, 0, 0, 0);
        st[t] = cc;
      }

      float mx = st[0][0];
#pragma unroll
      for (int t = 0; t < 4; ++t)
#pragma unroll
        for (int r = 0; r < 4; ++r) mx = fmaxf(mx, st[t][r]);
      mx = fmaxf(mx, __shfl_xor(mx, 16, 64));
      mx = fmaxf(mx, __shfl_xor(mx, 32, 64));
      const float mn = fmaxf(m_l[g], mx);
      const float al = __expf(m_l[g] - mn);
      m_l[g] = mn;
      float rs = 0.f;
      u16x4 pk[4];
#pragma unroll
      for (int t = 0; t < 4; ++t)
#pragma unroll
        for (int r = 0; r < 4; ++r) {
          const float p = __expf(st[t][r] - mn);
          rs += p;
          pk[t][r] = f2b(p);
        }
      rs += __shfl_xor(rs, 16, 64);
      rs += __shfl_xor(rs, 32, 64);
      l_l[g] = l_l[g] * al + rs;

      float arow[4];
#pragma unroll
      for (int r = 0; r < 4; ++r) arow[r] = __shfl(al, quad * 4 + r, 64);
#pragma unroll
      for (int t = 0; t < 4; ++t) {
        floatx4 o = accO[g][t];
        o[0] *= arow[0]; o[1] *= arow[1]; o[2] *= arow[2]; o[3] *= arow[3];
        accO[g][t] = o;
      }
#pragma unroll
      for (int t = 0; t < 4; ++t)
        *(u16x4*)(sP[wave] + (g*16 + lr) * ASTRIDE + t * 16 + quad * 4) = pk[t];
    }
    // no barrier: sP is per-wave; within-wave LDS write->read ordered by lgkmcnt

    // O += P @ V for both groups (V frags shared)
    short8 p00 = *(const short8*)(sP[wave] + lr * ASTRIDE + quad * 8);
    short8 p01 = *(const short8*)(sP[wave] + lr * ASTRIDE + 32 + quad * 8);
    short8 p10 = *(const short8*)(sP[wave] + (16 + lr) * ASTRIDE + quad * 8);
    short8 p11 = *(const short8*)(sP[wave] + (16 + lr) * ASTRIDE + 32 + quad * 8);
#pragma unroll
    for (int t = 0; t < 4; ++t) {
      short8 v0 = *(const short8*)(sV + (t*16 + lr) * ASTRIDE + quad * 8);
      short8 v1 = *(const short8*)(sV + (t*16 + lr) * ASTRIDE + 32 + quad * 8);
      accO[0][t] = __builtin_amdgcn_mfma_f32_16x16x32_bf16(p00, v0, accO[0][t], 0, 0, 0);
      accO[0][t] = __builtin_amdgcn_mfma_f32_16x16x32_bf16(p01, v1, accO[0][t], 0, 0, 0);
      accO[1][t] = __builtin_amdgcn_mfma_f32_16x16x32_bf16(p10, v0, accO[1][t], 0, 0, 0);
      accO[1][t] = __builtin_amdgcn_mfma_f32_16x16x32_bf16(p11, v1, accO[1][t], 0, 0, 0);
    }
  }

#pragma unroll
  for (int g = 0; g < 2; ++g) {
    float lrow[4];
#pragma unroll
    for (int r = 0; r < 4; ++r) lrow[r] = __shfl(l_l[g], quad * 4 + r, 64);
#pragma unroll
    for (int t = 0; t < 4; ++t)
#pragma unroll
      for (int r = 0; r < 4; ++r) {
        const int s = qb * 128 + g * 64 + wave * 16 + quad * 4 + r;
        const int d = h * 64 + t * 16 + lr;
        O[((size_t)(b * SS + s)) * DD + d] = f2b(accO[g][t][r] / lrow[r]);
      }
  }
}

// ---------------------------------------------------------------------------
extern "C" void kernel_launch(void* const* d_in, const int* in_sizes, int n_in,
                              void* d_out, int out_size, void* d_ws, size_t ws_size,
                              hipStream_t stream)
{
  const float* Qin = (const float*)d_in[0];
  const float* Kin = (const float*)d_in[1];
  const float* Vin = (const float*)d_in[2];
  const float* Wq  = (const float*)d_in[3];
  const float* bq  = (const float*)d_in[4];
  const float* Wk  = (const float*)d_in[5];
  const float* bk  = (const float*)d_in[6];
  const float* Wv  = (const float*)d_in[7];
  const float* bv  = (const float*)d_in[8];
  const float* Wo  = (const float*)d_in[9];
  const float* bo  = (const float*)d_in[10];
  float* out = (float*)d_out;

  const size_t TSZ = (size_t)MT * DD;   // 4M elements
  const size_t WSZ = (size_t)DD * DD;   // 1M elements
  dim3 blk(256);

  // d_out scratch for Wq/Wk/Wv bf16 (consumed by gemm_qkv; overwritten at end)
  u16* cWq = (u16*)d_out;
  u16* cWk = cWq + WSZ;
  u16* cWv = cWk + WSZ;

  u16* pQ   = (u16*)d_ws;
  u16* pK   = pQ  + TSZ;
  u16* pV   = pK  + TSZ;
  u16* wsVt = pV  + TSZ;
  u16* wsO  = wsVt + TSZ;

  if (ws_size >= (8*TSZ + WSZ) * sizeof(u16)) {
    u16* cQ  = wsO + TSZ;
    u16* cK  = cQ  + TSZ;
    u16* cV  = cK  + TSZ;
    u16* cWo = cV  + TSZ;
    cast_all<<<dim3(TSZ/8/256, 7), blk, 0, stream>>>(
        Qin, Kin, Vin, Wq, Wk, Wv, Wo, cQ, cK, cV, cWq, cWk, cWv, cWo);
    gemm_qkv_async<<<dim3(24, MT/128), blk, 0, stream>>>(
        cQ, cK, cV, cWq, cWk, cWv, bq, bk, bv, pQ, pK, pV);
    transpose_v<<<dim3(SS/64, HH, BB), blk, 0, stream>>>(pV, wsVt);
    attn<<<dim3(SS/128, HH, BB), blk, 0, stream>>>(pQ, pK, wsVt, wsO);
    gemm_out_async<<<dim3(DD/128, MT/128), blk, 0, stream>>>(wsO, cWo, bo, out);
  } else {
    cast_w3<<<dim3(WSZ/8/256, 3), blk, 0, stream>>>(Wq, Wk, Wv, cWq);
    gemm_qkv_fb<<<dim3(24, MT/128), blk, 0, stream>>>(
        Qin, Kin, Vin, cWq, cWk, cWv, bq, bk, bv, pQ, pK, pV);
    transpose_v<<<dim3(SS/64, HH, BB), blk, 0, stream>>>(pV, wsVt);
    attn<<<dim3(SS/128, HH, BB), blk, 0, stream>>>(pQ, pK, wsVt, wsO);
    gemm_out_fb<<<dim3(DD/128, MT/128), blk, 0, stream>>>(wsO, Wo, bo, out);
  }
}